// Round 19
// baseline (111.581 us; speedup 1.0000x reference)
//
#include <hip/hip_runtime.h>
#include <stdint.h>

typedef unsigned short u16;
typedef __bf16 bf16x8 __attribute__((ext_vector_type(8)));
typedef float f32x4 __attribute__((ext_vector_type(4)));
typedef float f32x16 __attribute__((ext_vector_type(16)));
typedef unsigned u32x4 __attribute__((ext_vector_type(4)));

#define DEVI __device__ __forceinline__

typedef __attribute__((address_space(1))) void gvoid;
typedef __attribute__((address_space(3))) void lvoid;

DEVI u16 f2b(float f) {
  unsigned x = __builtin_bit_cast(unsigned, f);
  return (u16)((x + 0x7fffu + ((x >> 16) & 1u)) >> 16);
}

DEVI float b2f(u16 u) { return __builtin_bit_cast(float, (unsigned)u << 16); }

DEVI float exp2g(float x) { return __builtin_amdgcn_exp2f(x); }

DEVI void gload_lds16(const void* g, void* l) {
  __builtin_amdgcn_global_load_lds((gvoid*)g, (lvoid*)l, 16, 0, 0);
}

// ---------------------------------------------------------------- fused cast
// ws bf16 image: xb (1M f4) | wqkvb (768K f4, first 256K scaled) | woutb (256K f4)
#define QSCALE 0.18033688011112042f

__global__ void cast_all(const float* __restrict__ x, const float* __restrict__ wqkv,
                         const float* __restrict__ wout, u16* __restrict__ outb) {
  int i = blockIdx.x * 256 + threadIdx.x;
  int stride = gridDim.x * 256;
  for (; i < 2097152; i += stride) {
    const float* src;
    float sc = 1.0f;
    if (i < 1048576) {
      src = x + 4 * (long)i;
    } else if (i < 1835008) {
      int j = i - 1048576;
      src = wqkv + 4 * (long)j;
      if (j < 262144) sc = QSCALE;
    } else {
      src = wout + 4 * (long)(i - 1835008);
    }
    float4 v = *(const float4*)src;
    ushort4 o;
    o.x = f2b(v.x * sc); o.y = f2b(v.y * sc); o.z = f2b(v.z * sc); o.w = f2b(v.w * sc);
    ((ushort4*)outb)[i] = o;
  }
}

// ---------------------------------------------------------------- GEMM C = A * B^T
// R14-proven single-buffer structure (32KB LDS, high occupancy).
// OUT=1: fp32 row-major.  OUT=2: QKV fused epilogue (logical N=3072):
//   col < 2048 -> qk row-major [4096][2048]; col >= 2048 -> vT blocked:
//   Cv2[((tok>>11)*16 + (f>>6))*131072 + (f&63)*2048 + (tok&2047)]
template<int OUT, int TM>
__global__ __launch_bounds__(256)
void gemm_bt(const u16* __restrict__ A, const u16* __restrict__ B, void* __restrict__ Cv,
             void* __restrict__ Cv2, int M, int N, int K) {
  constexpr int MI = TM / 32;
  __shared__ u16 lA[TM * 64];
  __shared__ u16 lB[128 * 64];
  const int tid = threadIdx.x;
  const int lane = tid & 63;
  const int lr = lane & 15;
  const int lg = lane >> 4;
  const int wid = tid >> 6;
  const long bm = (long)blockIdx.y * TM;
  const long bn = (long)blockIdx.x * 128;
  const int wr = (wid >> 1) * (TM / 2);
  const int wc = (wid & 1) * 64;

  f32x4 acc[MI][4];
#pragma unroll
  for (int i = 0; i < MI; ++i)
#pragma unroll
    for (int j = 0; j < 4; ++j)
      acc[i][j] = (f32x4){0.f, 0.f, 0.f, 0.f};

  for (int k0 = 0; k0 < K; k0 += 64) {
#pragma unroll
    for (int q = 0; q < MI; ++q) {
      int bi = tid + q * 256;
      int row = bi >> 3;
      int col = ((bi & 7) ^ (row & 7)) * 8;
      gload_lds16(A + (bm + row) * (long)K + k0 + col, (char*)lA + bi * 16);
    }
#pragma unroll
    for (int q = 0; q < 4; ++q) {
      int bi = tid + q * 256;
      int row = bi >> 3;
      int col = ((bi & 7) ^ (row & 7)) * 8;
      gload_lds16(B + (bn + row) * (long)K + k0 + col, (char*)lB + bi * 16);
    }
    __syncthreads();
#pragma unroll
    for (int kk = 0; kk < 2; ++kk) {
      bf16x8 af[MI], bfr[4];
      int kb = kk * 4 + lg;
#pragma unroll
      for (int mi = 0; mi < MI; ++mi) {
        int row = wr + mi * 16 + lr;
        af[mi] = *(const bf16x8*)((const char*)lA + row * 128 + ((kb ^ (row & 7)) << 4));
      }
#pragma unroll
      for (int ni = 0; ni < 4; ++ni) {
        int row = wc + ni * 16 + lr;
        bfr[ni] = *(const bf16x8*)((const char*)lB + row * 128 + ((kb ^ (row & 7)) << 4));
      }
#pragma unroll
      for (int mi = 0; mi < MI; ++mi)
#pragma unroll
        for (int ni = 0; ni < 4; ++ni)
          acc[mi][ni] = __builtin_amdgcn_mfma_f32_16x16x32_bf16(af[mi], bfr[ni], acc[mi][ni], 0, 0, 0);
    }
    __syncthreads();
  }

  if (OUT == 2 && bn >= 2048) {
#pragma unroll
    for (int mi = 0; mi < MI; ++mi)
#pragma unroll
      for (int ni = 0; ni < 4; ++ni) {
        long tok = bm + wr + mi * 16 + lg * 4;
        long ff = bn + wc + ni * 16 + lr - 2048;
        ushort4 st;
        st.x = f2b(acc[mi][ni][0]);
        st.y = f2b(acc[mi][ni][1]);
        st.z = f2b(acc[mi][ni][2]);
        st.w = f2b(acc[mi][ni][3]);
        u16* dst = (u16*)Cv2 + (((tok >> 11) << 4) + (ff >> 6)) * 131072 + (ff & 63) * 2048 + (tok & 2047);
        *(ushort4*)dst = st;
      }
  } else {
    const long strideN = (OUT == 2) ? 2048 : N;
#pragma unroll
    for (int mi = 0; mi < MI; ++mi)
#pragma unroll
      for (int ni = 0; ni < 4; ++ni)
#pragma unroll
        for (int r = 0; r < 4; ++r) {
          long row = bm + wr + mi * 16 + lg * 4 + r;
          long col = bn + wc + ni * 16 + lr;
          float v = acc[mi][ni][r];
          if (OUT == 1) ((float*)Cv)[row * strideN + col] = v;
          else          ((u16*)Cv)[row * strideN + col] = f2b(v);
        }
  }
}

// ---------------------------------------------------------------- flash attention v12b
// v11 per-wave structure (2-MFMA-per-LDS-read, 32x32x16 swapped MFMA, skip-max
// exp2 softmax, in-register P via permlane32_swap, K+V^T via global_load_lds,
// dbuf + vmcnt(0) barrier), split 2-way over the t-range (flash-decoding):
// grid 1024 = 4 blocks/CU = 4 waves/SIMD to hide the serial
// QK->exp2->pack->PV chain. Skip-max (global shift=0) makes partials
// combinable without rescale: o = o0+o1, l = l0+l1. Partial o written raw
// (bf16) to po0/po1 (separate pointers — no contiguity requirement),
// partial l fp32 to pl[ts]; combine kernel normalizes into po0 in-place.
__global__ __launch_bounds__(256, 2)
void attn_fwd(const u16* __restrict__ qk, const u16* __restrict__ vT,
              u16* __restrict__ po0, u16* __restrict__ po1, float* __restrict__ pl) {
  __shared__ char SM[33280];

  const int tid = threadIdx.x;
  const int lane = tid & 63;
  const int wid = tid >> 6;
  const int ql = lane & 31;
  const int h  = lane >> 5;
  const int th = wid >> 1;
  const int qw = wid & 1;

  // XCD swizzle: 1024 blocks, 8 XCDs, 128-block chunks (bijective)
  const int flat = blockIdx.x + (blockIdx.y << 4) + (blockIdx.z << 8);
  const int swz  = ((flat & 7) << 7) + (flat >> 3);
  const int qt = swz & 15;
  const int hd = (swz >> 4) & 15;
  const int zz = swz >> 8;
  const int b  = zz >> 1;      // batch
  const int ts = zz & 1;       // t-range half: [ts*1024, ts*1024+1024)

  const long rowbase = (long)b * 2048;
  const int qcol = hd * 64;
  const int kcol = 1024 + hd * 64;
  const int TSK = 64 * 2048;
  const long vhb = ((long)b * 16 + hd) * 131072;

  const int q0w = qt * 128 + qw * 64;
  bf16x8 qfA[4], qfB[4];
  {
    const u16* qpA = qk + (rowbase + q0w + ql) * 2048 + qcol + h * 8;
    const u16* qpB = qpA + 32 * 2048;
#pragma unroll
    for (int dblk = 0; dblk < 4; ++dblk) {
      qfA[dblk] = *(const bf16x8*)(qpA + dblk * 16);
      qfB[dblk] = *(const bf16x8*)(qpB + dblk * 16);
    }
  }

  float lA = 0.f, lB = 0.f;
  f32x16 oA[2], oB[2];
#pragma unroll
  for (int d = 0; d < 2; ++d)
#pragma unroll
    for (int r = 0; r < 16; ++r) { oA[d][r] = 0.f; oB[d][r] = 0.f; }

  const int c0 = tid, c1 = tid + 256;
  const int rk0 = c0 >> 3, ck0 = ((c0 & 7) ^ (rk0 & 7)) * 8;
  const int rk1 = c1 >> 3, ck1 = ((c1 & 7) ^ (rk1 & 7)) * 8;
  const int d0 = c0 * 16, d1 = c1 * 16;
  const u16* kp0 = qk + (rowbase + ts * 1024 + rk0) * 2048 + kcol + ck0;
  const u16* kp1 = qk + (rowbase + ts * 1024 + rk1) * 2048 + kcol + ck1;
  const u16* vp0 = vT + vhb + rk0 * 2048 + ts * 1024 + ck0;
  const u16* vp1 = vT + vhb + rk1 * 2048 + ts * 1024 + ck1;

  gload_lds16(kp0, SM + d0);          gload_lds16(kp1, SM + d1);
  gload_lds16(vp0, SM + 16384 + d0);  gload_lds16(vp1, SM + 16384 + d1);
  kp0 += TSK; kp1 += TSK; vp0 += 64; vp1 += 64;
  asm volatile("s_waitcnt vmcnt(0)" ::: "memory");
  __builtin_amdgcn_s_barrier();
  __builtin_amdgcn_sched_barrier(0);

  // 16 tiles of 64 t (8 outer x 2 unrolled)
  for (int tt = 0; tt < 8; ++tt) {
#pragma unroll
    for (int P = 0; P < 2; ++P) {
      char* KsCur = SM + P * 8192;
      char* VsCur = SM + 16384 + P * 8192;
      char* KsNxt = SM + (P ^ 1) * 8192;
      char* VsNxt = SM + 16384 + (P ^ 1) * 8192;

      // issue tile t+1 (tail overreads land in dead ring buffer; mapped ws)
      gload_lds16(kp0, KsNxt + d0);  gload_lds16(kp1, KsNxt + d1);
      gload_lds16(vp0, VsNxt + d0);  gload_lds16(vp1, VsNxt + d1);
      kp0 += TSK; kp1 += TSK; vp0 += 64; vp1 += 64;

      f32x16 sA, sB;
#pragma unroll
      for (int r = 0; r < 16; ++r) { sA[r] = 0.f; sB[r] = 0.f; }
      const char* Kb = KsCur + (th * 32 + ql) * 128;
      __builtin_amdgcn_s_setprio(1);
#pragma unroll
      for (int kd = 0; kd < 4; ++kd) {
        bf16x8 kf = *(const bf16x8*)(Kb + (((kd * 2 + h) ^ (ql & 7)) << 4));
        sA = __builtin_amdgcn_mfma_f32_32x32x16_bf16(kf, qfA[kd], sA, 0, 0, 0);
        sB = __builtin_amdgcn_mfma_f32_32x32x16_bf16(kf, qfB[kd], sB, 0, 0, 0);
      }
      __builtin_amdgcn_s_setprio(0);

#pragma unroll
      for (int r = 0; r < 16; ++r) sA[r] = exp2g(sA[r]);
#pragma unroll
      for (int r = 0; r < 16; ++r) sB[r] = exp2g(sB[r]);
      lA += (((sA[0] + sA[1]) + (sA[2] + sA[3])) + ((sA[4] + sA[5]) + (sA[6] + sA[7])))
          + (((sA[8] + sA[9]) + (sA[10] + sA[11])) + ((sA[12] + sA[13]) + (sA[14] + sA[15])));
      lB += (((sB[0] + sB[1]) + (sB[2] + sB[3])) + ((sB[4] + sB[5]) + (sB[6] + sB[7])))
          + (((sB[8] + sB[9]) + (sB[10] + sB[11])) + ((sB[12] + sB[13]) + (sB[14] + sB[15])));

      unsigned wA[8], wB[8];
#pragma unroll
      for (int m = 0; m < 8; ++m) {
        asm("v_cvt_pk_bf16_f32 %0, %1, %2" : "=v"(wA[m]) : "v"(sA[2 * m]), "v"(sA[2 * m + 1]));
        asm("v_cvt_pk_bf16_f32 %0, %1, %2" : "=v"(wB[m]) : "v"(sB[2 * m]), "v"(sB[2 * m + 1]));
      }

      bf16x8 pbA[2], pbB[2];
#pragma unroll
      for (int ks = 0; ks < 2; ++ks) {
        unsigned a0 = wA[4 * ks],     a2 = wA[4 * ks + 2];
        unsigned a1 = wA[4 * ks + 1], a3 = wA[4 * ks + 3];
        asm("s_nop 1\n\tv_permlane32_swap_b32 %0, %1" : "+v"(a0), "+v"(a2));
        asm("s_nop 1\n\tv_permlane32_swap_b32 %0, %1" : "+v"(a1), "+v"(a3));
        u32x4 t; t[0] = a0; t[1] = a1; t[2] = a2; t[3] = a3;
        pbA[ks] = __builtin_bit_cast(bf16x8, t);
        unsigned b0 = wB[4 * ks],     b2 = wB[4 * ks + 2];
        unsigned b1 = wB[4 * ks + 1], b3 = wB[4 * ks + 3];
        asm("s_nop 1\n\tv_permlane32_swap_b32 %0, %1" : "+v"(b0), "+v"(b2));
        asm("s_nop 1\n\tv_permlane32_swap_b32 %0, %1" : "+v"(b1), "+v"(b3));
        u32x4 u; u[0] = b0; u[1] = b1; u[2] = b2; u[3] = b3;
        pbB[ks] = __builtin_bit_cast(bf16x8, u);
      }

      __builtin_amdgcn_s_setprio(1);
#pragma unroll
      for (int dblk = 0; dblk < 2; ++dblk) {
        const char* Vb = VsCur + (dblk * 32 + ql) * 128;
#pragma unroll
        for (int ks = 0; ks < 2; ++ks) {
          bf16x8 vf = *(const bf16x8*)(Vb + (((th * 4 + ks * 2 + h) ^ (ql & 7)) << 4));
          oA[dblk] = __builtin_amdgcn_mfma_f32_32x32x16_bf16(vf, pbA[ks], oA[dblk], 0, 0, 0);
          oB[dblk] = __builtin_amdgcn_mfma_f32_32x32x16_bf16(vf, pbB[ks], oB[dblk], 0, 0, 0);
        }
      }
      __builtin_amdgcn_s_setprio(0);

      asm volatile("s_waitcnt vmcnt(0)" ::: "memory");
      __builtin_amdgcn_s_barrier();
      __builtin_amdgcn_sched_barrier(0);
    }
  }
  __syncthreads();

  // ---- cross-half l sums (lane l <-> l^32 hold complementary t-subsets)
  float pxA = lA, pyA = lA;
  asm("s_nop 1\n\tv_permlane32_swap_b32 %0, %1" : "+v"(pxA), "+v"(pyA));
  float lwA = lA + (h ? pxA : pyA);
  float pxB = lB, pyB = lB;
  asm("s_nop 1\n\tv_permlane32_swap_b32 %0, %1" : "+v"(pxB), "+v"(pyB));
  float lwB = lB + (h ? pxB : pyB);

  // ---- epilogue combine across t-halves; write RAW partial o (bf16) + l
  if (th == 1) {
    char* regA = SM + (qw * 2 + 0) * 8192;
    char* regB = SM + (qw * 2 + 1) * 8192;
#pragma unroll
    for (int dblk = 0; dblk < 2; ++dblk)
#pragma unroll
      for (int r = 0; r < 16; ++r) {
        int dl = dblk * 32 + (r & 3) + 8 * (r >> 2) + 4 * h;
        *(float*)(regA + dl * 128 + ql * 4) = oA[dblk][r];
        *(float*)(regB + dl * 128 + ql * 4) = oB[dblk][r];
      }
    if (h == 0) {
      *(float*)(SM + 32768 + (qw * 2 + 0) * 128 + ql * 4) = lwA;
      *(float*)(SM + 32768 + (qw * 2 + 1) * 128 + ql * 4) = lwB;
    }
  }
  __syncthreads();
  if (th == 0) {
    const char* regA = SM + (qw * 2 + 0) * 8192;
    const char* regB = SM + (qw * 2 + 1) * 8192;
#pragma unroll
    for (int dblk = 0; dblk < 2; ++dblk)
#pragma unroll
      for (int r = 0; r < 16; ++r) {
        int dl = dblk * 32 + (r & 3) + 8 * (r >> 2) + 4 * h;
        oA[dblk][r] += *(const float*)(regA + dl * 128 + ql * 4);
        oB[dblk][r] += *(const float*)(regB + dl * 128 + ql * 4);
      }
    float ltotA = lwA + *(const float*)(SM + 32768 + (qw * 2 + 0) * 128 + ql * 4);
    float ltotB = lwB + *(const float*)(SM + 32768 + (qw * 2 + 1) * 128 + ql * 4);
    if (h == 0) {
      float* plb = pl + (long)ts * 65536 + ((long)b * 16 + hd) * 2048;
      plb[q0w + ql]      = ltotA;
      plb[q0w + 32 + ql] = ltotB;
    }
    long rowA = rowbase + q0w + ql;
    long rowB = rowA + 32;
    u16* pob = ts ? po1 : po0;
#pragma unroll
    for (int dblk = 0; dblk < 2; ++dblk)
#pragma unroll
      for (int m = 0; m < 4; ++m) {
        ushort4 stA;
        stA.x = f2b(oA[dblk][4 * m + 0]);
        stA.y = f2b(oA[dblk][4 * m + 1]);
        stA.z = f2b(oA[dblk][4 * m + 2]);
        stA.w = f2b(oA[dblk][4 * m + 3]);
        *(ushort4*)(pob + rowA * 1024 + qcol + dblk * 32 + 8 * m + 4 * h) = stA;
        ushort4 stB;
        stB.x = f2b(oB[dblk][4 * m + 0]);
        stB.y = f2b(oB[dblk][4 * m + 1]);
        stB.z = f2b(oB[dblk][4 * m + 2]);
        stB.w = f2b(oB[dblk][4 * m + 3]);
        *(ushort4*)(pob + rowB * 1024 + qcol + dblk * 32 + 8 * m + 4 * h) = stB;
      }
  }
}

// ---------------------------------------------------------------- combine
// po0[i] = (po0[i] + po1[i]) / (l0 + l1); in-place over po0 (per-thread
// read-then-write, no cross-thread hazard). 8 bf16 per thread.
__global__ __launch_bounds__(256)
void attn_combine(u16* __restrict__ po0, const u16* __restrict__ po1,
                  const float* __restrict__ pl) {
  long i = (long)blockIdx.x * 256 + threadIdx.x;   // 0 .. 524287
  long base = i * 8;
  int row = (int)(base >> 10);
  int col = (int)(base & 1023);
  int hd = col >> 6;
  int b = row >> 11;
  int q = row & 2047;
  long lidx = ((long)b * 16 + hd) * 2048 + q;
  float inv = 1.0f / (pl[lidx] + pl[65536 + lidx]);

  ushort4 a0 = *(const ushort4*)(po0 + base);
  ushort4 a1 = *(const ushort4*)(po0 + base + 4);
  ushort4 b0 = *(const ushort4*)(po1 + base);
  ushort4 b1 = *(const ushort4*)(po1 + base + 4);
  ushort4 o0, o1;
  o0.x = f2b((b2f(a0.x) + b2f(b0.x)) * inv);
  o0.y = f2b((b2f(a0.y) + b2f(b0.y)) * inv);
  o0.z = f2b((b2f(a0.z) + b2f(b0.z)) * inv);
  o0.w = f2b((b2f(a0.w) + b2f(b0.w)) * inv);
  o1.x = f2b((b2f(a1.x) + b2f(b1.x)) * inv);
  o1.y = f2b((b2f(a1.y) + b2f(b1.y)) * inv);
  o1.z = f2b((b2f(a1.z) + b2f(b1.z)) * inv);
  o1.w = f2b((b2f(a1.w) + b2f(b1.w)) * inv);
  *(ushort4*)(po0 + base) = o0;
  *(ushort4*)(po0 + base + 4) = o1;
}

// ---------------------------------------------------------------- launch
// ws map (48 MB total, all offsets fixed):
//   [ 0,        8388608)  xb (bf16 x; dead after QKV gemm)  -> po1 partial
//   [ 8388608, 14680064)  wqkvb (dead after QKV gemm)       -> pl (512 KB)
//   [14680064, 16777216)  woutb (LIVE until gemm2)
//   [16777216, 33554432)  qk  [4096][2048]
//   [33554432, 41943040)  vT  [bh][64][2048]
//   [41943040, 50331648)  po0 partial -> combined attn (gemm2 A input)
extern "C" void kernel_launch(void* const* d_in, const int* in_sizes, int n_in,
                              void* d_out, int out_size, void* d_ws, size_t ws_size,
                              hipStream_t stream) {
  const float* x     = (const float*)d_in[0];  // [2,2048,1024]
  const float* w_qkv = (const float*)d_in[1];  // [3072,1024]
  const float* w_out = (const float*)d_in[2];  // [1024,1024]
  float* out = (float*)d_out;                  // [2,2048,1024] fp32

  char* ws = (char*)d_ws;
  u16* xb    = (u16*)(ws);
  u16* wqkvb = (u16*)(ws + 8388608);
  u16* woutb = (u16*)(ws + 14680064);
  u16* qk    = (u16*)(ws + 16777216);
  u16* vT    = (u16*)(ws + 33554432);
  u16* po0   = (u16*)(ws + 41943040);
  u16* po1   = (u16*)(ws);                     // reuses xb (dead)
  float* pl  = (float*)(ws + 8388608);         // reuses wqkvb (dead), 512 KB

  cast_all<<<2048, 256, 0, stream>>>(x, w_qkv, w_out, xb);

  // QKV projection (R14-proven 128-tile): Q,K -> qk row-major; V -> vT blocked
  gemm_bt<2, 128><<<dim3(24, 32), 256, 0, stream>>>(xb, wqkvb, qk, vT, 4096, 3072, 1024);

  // attention, 2-way t-split (flash-decoding): partials to po0/po1 + pl
  attn_fwd<<<dim3(16, 16, 4), 256, 0, stream>>>(qk, vT, po0, po1, pl);

  // combine: po0 <- (po0 + po1) / (l0 + l1)
  attn_combine<<<2048, 256, 0, stream>>>(po0, po1, pl);

  // output projection reads combined attn from po0
  gemm_bt<1, 64><<<dim3(8, 64), 256, 0, stream>>>(po0, woutb, out, nullptr, 4096, 1024, 1024);
}

// Round 20
// 106.961 us; speedup vs baseline: 1.0432x; 1.0432x over previous
//
#include <hip/hip_runtime.h>
#include <stdint.h>

typedef unsigned short u16;
typedef __bf16 bf16x8 __attribute__((ext_vector_type(8)));
typedef float f32x4 __attribute__((ext_vector_type(4)));
typedef float f32x16 __attribute__((ext_vector_type(16)));
typedef unsigned u32x4 __attribute__((ext_vector_type(4)));

#define DEVI __device__ __forceinline__

typedef __attribute__((address_space(1))) void gvoid;
typedef __attribute__((address_space(3))) void lvoid;

DEVI u16 f2b(float f) {
  unsigned x = __builtin_bit_cast(unsigned, f);
  return (u16)((x + 0x7fffu + ((x >> 16) & 1u)) >> 16);
}

DEVI float exp2g(float x) { return __builtin_amdgcn_exp2f(x); }

DEVI void gload_lds16(const void* g, void* l) {
  __builtin_amdgcn_global_load_lds((gvoid*)g, (lvoid*)l, 16, 0, 0);
}

#define BARRIER() do { asm volatile("" ::: "memory"); __builtin_amdgcn_s_barrier(); __builtin_amdgcn_sched_barrier(0); } while (0)
#define LGKM0()   do { asm volatile("s_waitcnt lgkmcnt(0)" ::: "memory"); __builtin_amdgcn_sched_barrier(0); } while (0)

// ---------------------------------------------------------------- fused cast
// ws bf16 image: xb (1M f4) | wqkvb (768K f4, first 256K scaled) | woutb (256K f4)
#define QSCALE 0.18033688011112042f

__global__ void cast_all(const float* __restrict__ x, const float* __restrict__ wqkv,
                         const float* __restrict__ wout, u16* __restrict__ outb) {
  int i = blockIdx.x * 256 + threadIdx.x;
  int stride = gridDim.x * 256;
  for (; i < 2097152; i += stride) {
    const float* src;
    float sc = 1.0f;
    if (i < 1048576) {
      src = x + 4 * (long)i;
    } else if (i < 1835008) {
      int j = i - 1048576;
      src = wqkv + 4 * (long)j;
      if (j < 262144) sc = QSCALE;
    } else {
      src = wout + 4 * (long)(i - 1835008);
    }
    float4 v = *(const float4*)src;
    ushort4 o;
    o.x = f2b(v.x * sc); o.y = f2b(v.y * sc); o.z = f2b(v.z * sc); o.w = f2b(v.w * sc);
    ((ushort4*)outb)[i] = o;
  }
}

// ---------------------------------------------------------------- 8-phase 256x256 QKV GEMM
// 512 thr, 8 waves (2M x 4N), BK=64, 128 KB LDS: A[2 buf][2 half][128x64],
// B likewise @65536. Chunk-XOR swizzle (proven 0-conflict). Per K-tile, 4
// phases = C-quadrants; each phase: {ds_reads ; stage 1 half-tile (2 gload) ;
// barrier ; lgkmcnt(0) ; setprio + 16 MFMA ; barrier}. Stage queue from LDS
// last-read constraints: p0->(T+1).B0, p1->(T+1).B1 (other buf), p2->(T+2).A0,
// p3->(T+2).A1 (own buf; A last read at p1). Tile-top s_waitcnt vmcnt(4)
// (2 half-tiles in flight) + barrier — never vmcnt(0) in the loop.
// Fused epilogue: bn<2048 -> qk row-major [4096][2048]; bn>=2048 -> vT blocked.
__global__ __launch_bounds__(512, 2)
void gemm_qkv(const u16* __restrict__ A, const u16* __restrict__ B,
              u16* __restrict__ qk, u16* __restrict__ vT) {
  __shared__ char SM[131072];
  const int tid = threadIdx.x;
  const int lane = tid & 63;
  const int lr = lane & 15;
  const int lg = lane >> 4;
  const int wid = tid >> 6;
  const int wm = wid >> 2;             // 0..1  (row half of 256)
  const int wn = wid & 3;              // 0..3  (64-col span)
  const long bm = (long)blockIdx.y * 256;
  const long bn = (long)blockIdx.x * 256;

  // staging: thread's 2 chunks per half-tile; rows r0 and r0+64, same swz col
  const int r0 = tid >> 3;             // 0..63
  const int c0 = ((tid & 7) ^ (r0 & 7)) * 8;
  const int dst0 = tid * 16;
  const u16* tA = A + (bm + r0) * 1024 + c0;
  const u16* tB = B + (bn + r0) * 1024 + c0;

#define STAGE_A(buf, h, ko) do { \
    gload_lds16(tA + (h) * 131072 + (ko),         SM + (buf) * 32768 + (h) * 16384 + dst0); \
    gload_lds16(tA + (h) * 131072 + (ko) + 65536, SM + (buf) * 32768 + (h) * 16384 + dst0 + 8192); } while (0)
#define STAGE_B(buf, h, ko) do { \
    gload_lds16(tB + (h) * 131072 + (ko),         SM + 65536 + (buf) * 32768 + (h) * 16384 + dst0); \
    gload_lds16(tB + (h) * 131072 + (ko) + 65536, SM + 65536 + (buf) * 32768 + (h) * 16384 + dst0 + 8192); } while (0)

  f32x4 acc[8][4];
#pragma unroll
  for (int i = 0; i < 8; ++i)
#pragma unroll
    for (int j = 0; j < 4; ++j)
      acc[i][j] = (f32x4){0.f, 0.f, 0.f, 0.f};

  const int wmo = wm * 16384;          // A half offset for this wave
  const int bho = (wn >> 1) * 16384;   // B half offset
  const int bro = (wn & 1) * 64;       // B local row base within half

  // ---- prologue: queue = t0.A0,A1,B0,B1, t1.A0,A1 (12 loads)
  STAGE_A(0, 0, 0);  STAGE_A(0, 1, 0);
  STAGE_B(0, 0, 0);  STAGE_B(0, 1, 0);
  STAGE_A(1, 0, 64); STAGE_A(1, 1, 64);

  for (int T = 0; T < 16; ++T) {
    const int pb = T & 1;
    const int koB = (T + 1) * 64;
    const int koA = (T + 2) * 64;
    const char* LA = SM + pb * 32768 + wmo;
    const char* LB = SM + 65536 + pb * 32768 + bho;

    // ---- tile top: all 4 half-tiles of T landed (2 newest HT may fly)
    asm volatile("s_waitcnt vmcnt(4)" ::: "memory");
    __builtin_amdgcn_s_barrier();
    __builtin_amdgcn_sched_barrier(0);

    bf16x8 a0[4][2], a1[4][2], bfr[2][2];

    // ---- p0: read A mi0-3 (8) + B ni0-1 (4); stage (T+1).B0; Q(0,0)
#pragma unroll
    for (int mi = 0; mi < 4; ++mi)
#pragma unroll
      for (int kk = 0; kk < 2; ++kk) {
        int r = mi * 16 + lr;
        a0[mi][kk] = *(const bf16x8*)(LA + r * 128 + (((kk * 4 + lg) ^ (r & 7)) << 4));
      }
#pragma unroll
    for (int ni = 0; ni < 2; ++ni)
#pragma unroll
      for (int kk = 0; kk < 2; ++kk) {
        int r = bro + ni * 16 + lr;
        bfr[ni][kk] = *(const bf16x8*)(LB + r * 128 + (((kk * 4 + lg) ^ (r & 7)) << 4));
      }
    STAGE_B(pb ^ 1, 0, koB);
    BARRIER();
    LGKM0();
    __builtin_amdgcn_s_setprio(1);
#pragma unroll
    for (int mi = 0; mi < 4; ++mi)
#pragma unroll
      for (int ni = 0; ni < 2; ++ni)
#pragma unroll
        for (int kk = 0; kk < 2; ++kk)
          acc[mi][ni] = __builtin_amdgcn_mfma_f32_16x16x32_bf16(a0[mi][kk], bfr[ni][kk], acc[mi][ni], 0, 0, 0);
    __builtin_amdgcn_s_setprio(0);
    BARRIER();

    // ---- p1: read A mi4-7 (8); stage (T+1).B1; Q(1,0)
#pragma unroll
    for (int mi = 0; mi < 4; ++mi)
#pragma unroll
      for (int kk = 0; kk < 2; ++kk) {
        int r = (mi + 4) * 16 + lr;
        a1[mi][kk] = *(const bf16x8*)(LA + r * 128 + (((kk * 4 + lg) ^ (r & 7)) << 4));
      }
    STAGE_B(pb ^ 1, 1, koB);
    BARRIER();
    LGKM0();
    __builtin_amdgcn_s_setprio(1);
#pragma unroll
    for (int mi = 0; mi < 4; ++mi)
#pragma unroll
      for (int ni = 0; ni < 2; ++ni)
#pragma unroll
        for (int kk = 0; kk < 2; ++kk)
          acc[4 + mi][ni] = __builtin_amdgcn_mfma_f32_16x16x32_bf16(a1[mi][kk], bfr[ni][kk], acc[4 + mi][ni], 0, 0, 0);
    __builtin_amdgcn_s_setprio(0);
    BARRIER();

    // ---- p2: read B ni2-3 (4, overwrite bfr); stage (T+2).A0; Q(0,1)
#pragma unroll
    for (int ni = 0; ni < 2; ++ni)
#pragma unroll
      for (int kk = 0; kk < 2; ++kk) {
        int r = bro + (ni + 2) * 16 + lr;
        bfr[ni][kk] = *(const bf16x8*)(LB + r * 128 + (((kk * 4 + lg) ^ (r & 7)) << 4));
      }
    STAGE_A(pb, 0, koA);
    BARRIER();
    LGKM0();
    __builtin_amdgcn_s_setprio(1);
#pragma unroll
    for (int mi = 0; mi < 4; ++mi)
#pragma unroll
      for (int ni = 0; ni < 2; ++ni)
#pragma unroll
        for (int kk = 0; kk < 2; ++kk)
          acc[mi][2 + ni] = __builtin_amdgcn_mfma_f32_16x16x32_bf16(a0[mi][kk], bfr[ni][kk], acc[mi][2 + ni], 0, 0, 0);
    __builtin_amdgcn_s_setprio(0);
    BARRIER();

    // ---- p3: no reads; stage (T+2).A1; Q(1,1)
    STAGE_A(pb, 1, koA);
    BARRIER();
    LGKM0();
    __builtin_amdgcn_s_setprio(1);
#pragma unroll
    for (int mi = 0; mi < 4; ++mi)
#pragma unroll
      for (int ni = 0; ni < 2; ++ni)
#pragma unroll
        for (int kk = 0; kk < 2; ++kk)
          acc[4 + mi][2 + ni] = __builtin_amdgcn_mfma_f32_16x16x32_bf16(a1[mi][kk], bfr[ni][kk], acc[4 + mi][2 + ni], 0, 0, 0);
    __builtin_amdgcn_s_setprio(0);
    BARRIER();
  }

  // drain tail stages (their LDS writes are dead)
  asm volatile("s_waitcnt vmcnt(0)" ::: "memory");

  // ---- epilogue (block-uniform Q/K vs V split at col 2048)
  const int wr = wm * 128;
  const int wc = wn * 64;
  if (bn >= 2048) {
#pragma unroll
    for (int mi = 0; mi < 8; ++mi)
#pragma unroll
      for (int ni = 0; ni < 4; ++ni) {
        long tok = bm + wr + mi * 16 + lg * 4;     // +r consecutive
        long f = bn + wc + ni * 16 + lr - 2048;
        ushort4 st;
        st.x = f2b(acc[mi][ni][0]);
        st.y = f2b(acc[mi][ni][1]);
        st.z = f2b(acc[mi][ni][2]);
        st.w = f2b(acc[mi][ni][3]);
        u16* dst = vT + (((tok >> 11) << 4) + (f >> 6)) * 131072 + (f & 63) * 2048 + (tok & 2047);
        *(ushort4*)dst = st;
      }
  } else {
#pragma unroll
    for (int mi = 0; mi < 8; ++mi)
#pragma unroll
      for (int ni = 0; ni < 4; ++ni)
#pragma unroll
        for (int r = 0; r < 4; ++r) {
          long row = bm + wr + mi * 16 + lg * 4 + r;
          long col = bn + wc + ni * 16 + lr;
          qk[row * 2048 + col] = f2b(acc[mi][ni][r]);
        }
  }
#undef STAGE_A
#undef STAGE_B
}

// ---------------------------------------------------------------- GEMM C = A * B^T
// (R14-proven single-buffer structure; output projection, fp32 out)
template<int TM>
__global__ __launch_bounds__(256)
void gemm_out(const u16* __restrict__ A, const u16* __restrict__ B, float* __restrict__ Cv,
              int M, int N, int K) {
  constexpr int MI = TM / 32;
  __shared__ u16 lA[TM * 64];
  __shared__ u16 lB[128 * 64];
  const int tid = threadIdx.x;
  const int lane = tid & 63;
  const int lr = lane & 15;
  const int lg = lane >> 4;
  const int wid = tid >> 6;
  const long bm = (long)blockIdx.y * TM;
  const long bn = (long)blockIdx.x * 128;
  const int wr = (wid >> 1) * (TM / 2);
  const int wc = (wid & 1) * 64;

  f32x4 acc[MI][4];
#pragma unroll
  for (int i = 0; i < MI; ++i)
#pragma unroll
    for (int j = 0; j < 4; ++j)
      acc[i][j] = (f32x4){0.f, 0.f, 0.f, 0.f};

  for (int k0 = 0; k0 < K; k0 += 64) {
#pragma unroll
    for (int q = 0; q < MI; ++q) {
      int bi = tid + q * 256;
      int row = bi >> 3;
      int col = ((bi & 7) ^ (row & 7)) * 8;
      gload_lds16(A + (bm + row) * (long)K + k0 + col, (char*)lA + bi * 16);
    }
#pragma unroll
    for (int q = 0; q < 4; ++q) {
      int bi = tid + q * 256;
      int row = bi >> 3;
      int col = ((bi & 7) ^ (row & 7)) * 8;
      gload_lds16(B + (bn + row) * (long)K + k0 + col, (char*)lB + bi * 16);
    }
    __syncthreads();
#pragma unroll
    for (int kk = 0; kk < 2; ++kk) {
      bf16x8 af[MI], bfr[4];
      int kb = kk * 4 + lg;
#pragma unroll
      for (int mi = 0; mi < MI; ++mi) {
        int row = wr + mi * 16 + lr;
        af[mi] = *(const bf16x8*)((const char*)lA + row * 128 + ((kb ^ (row & 7)) << 4));
      }
#pragma unroll
      for (int ni = 0; ni < 4; ++ni) {
        int row = wc + ni * 16 + lr;
        bfr[ni] = *(const bf16x8*)((const char*)lB + row * 128 + ((kb ^ (row & 7)) << 4));
      }
#pragma unroll
      for (int mi = 0; mi < MI; ++mi)
#pragma unroll
        for (int ni = 0; ni < 4; ++ni)
          acc[mi][ni] = __builtin_amdgcn_mfma_f32_16x16x32_bf16(af[mi], bfr[ni], acc[mi][ni], 0, 0, 0);
    }
    __syncthreads();
  }
#pragma unroll
  for (int mi = 0; mi < MI; ++mi)
#pragma unroll
    for (int ni = 0; ni < 4; ++ni)
#pragma unroll
      for (int r = 0; r < 4; ++r) {
        long row = bm + wr + mi * 16 + lg * 4 + r;
        long col = bn + wc + ni * 16 + lr;
        Cv[row * (long)N + col] = acc[mi][ni][r];
      }
}

// ---------------------------------------------------------------- flash attention v11
// (R14/R16-proven) 2-MFMA-per-LDS-read: each wave computes TWO 32-q blocks
// sharing every K/V fragment read. 4 waves/block, q-tile 128, grid 512,
// 32x32x16 swapped MFMA, skip-max exp2 softmax, in-register P via
// permlane32_swap, K+V^T via global_load_lds, dbuf + vmcnt(0) barrier,
// XCD-aware bijective swizzle.
__global__ __launch_bounds__(256, 2)
void attn_fwd(const u16* __restrict__ qk, const u16* __restrict__ vT,
              u16* __restrict__ outb) {
  __shared__ char SM[33280];

  const int tid = threadIdx.x;
  const int lane = tid & 63;
  const int wid = tid >> 6;
  const int ql = lane & 31;
  const int h  = lane >> 5;
  const int th = wid >> 1;
  const int qw = wid & 1;

  const int flat = blockIdx.x + (blockIdx.y << 4) + (blockIdx.z << 8);
  const int swz  = ((flat & 7) << 6) + (flat >> 3);
  const int qt = swz & 15;
  const int hd = (swz >> 4) & 15;
  const int b  = swz >> 8;

  const long rowbase = (long)b * 2048;
  const int qcol = hd * 64;
  const int kcol = 1024 + hd * 64;
  const int TSK = 64 * 2048;
  const long vhb = ((long)b * 16 + hd) * 131072;

  const int q0w = qt * 128 + qw * 64;
  bf16x8 qfA[4], qfB[4];
  {
    const u16* qpA = qk + (rowbase + q0w + ql) * 2048 + qcol + h * 8;
    const u16* qpB = qpA + 32 * 2048;
#pragma unroll
    for (int dblk = 0; dblk < 4; ++dblk) {
      qfA[dblk] = *(const bf16x8*)(qpA + dblk * 16);
      qfB[dblk] = *(const bf16x8*)(qpB + dblk * 16);
    }
  }

  float lA = 0.f, lB = 0.f;
  f32x16 oA[2], oB[2];
#pragma unroll
  for (int d = 0; d < 2; ++d)
#pragma unroll
    for (int r = 0; r < 16; ++r) { oA[d][r] = 0.f; oB[d][r] = 0.f; }

  const int c0 = tid, c1 = tid + 256;
  const int rk0 = c0 >> 3, ck0 = ((c0 & 7) ^ (rk0 & 7)) * 8;
  const int rk1 = c1 >> 3, ck1 = ((c1 & 7) ^ (rk1 & 7)) * 8;
  const int d0 = c0 * 16, d1 = c1 * 16;
  const u16* kp0 = qk + (rowbase + rk0) * 2048 + kcol + ck0;
  const u16* kp1 = qk + (rowbase + rk1) * 2048 + kcol + ck1;
  const u16* vp0 = vT + vhb + rk0 * 2048 + ck0;
  const u16* vp1 = vT + vhb + rk1 * 2048 + ck1;

  gload_lds16(kp0, SM + d0);          gload_lds16(kp1, SM + d1);
  gload_lds16(vp0, SM + 16384 + d0);  gload_lds16(vp1, SM + 16384 + d1);
  kp0 += TSK; kp1 += TSK; vp0 += 64; vp1 += 64;
  asm volatile("s_waitcnt vmcnt(0)" ::: "memory");
  __builtin_amdgcn_s_barrier();
  __builtin_amdgcn_sched_barrier(0);

  for (int tt = 0; tt < 16; ++tt) {
#pragma unroll
    for (int P = 0; P < 2; ++P) {
      char* KsCur = SM + P * 8192;
      char* VsCur = SM + 16384 + P * 8192;
      char* KsNxt = SM + (P ^ 1) * 8192;
      char* VsNxt = SM + 16384 + (P ^ 1) * 8192;

      gload_lds16(kp0, KsNxt + d0);  gload_lds16(kp1, KsNxt + d1);
      gload_lds16(vp0, VsNxt + d0);  gload_lds16(vp1, VsNxt + d1);
      kp0 += TSK; kp1 += TSK; vp0 += 64; vp1 += 64;

      f32x16 sA, sB;
#pragma unroll
      for (int r = 0; r < 16; ++r) { sA[r] = 0.f; sB[r] = 0.f; }
      const char* Kb = KsCur + (th * 32 + ql) * 128;
      __builtin_amdgcn_s_setprio(1);
#pragma unroll
      for (int kd = 0; kd < 4; ++kd) {
        bf16x8 kf = *(const bf16x8*)(Kb + (((kd * 2 + h) ^ (ql & 7)) << 4));
        sA = __builtin_amdgcn_mfma_f32_32x32x16_bf16(kf, qfA[kd], sA, 0, 0, 0);
        sB = __builtin_amdgcn_mfma_f32_32x32x16_bf16(kf, qfB[kd], sB, 0, 0, 0);
      }
      __builtin_amdgcn_s_setprio(0);

#pragma unroll
      for (int r = 0; r < 16; ++r) sA[r] = exp2g(sA[r]);
#pragma unroll
      for (int r = 0; r < 16; ++r) sB[r] = exp2g(sB[r]);
      lA += (((sA[0] + sA[1]) + (sA[2] + sA[3])) + ((sA[4] + sA[5]) + (sA[6] + sA[7])))
          + (((sA[8] + sA[9]) + (sA[10] + sA[11])) + ((sA[12] + sA[13]) + (sA[14] + sA[15])));
      lB += (((sB[0] + sB[1]) + (sB[2] + sB[3])) + ((sB[4] + sB[5]) + (sB[6] + sB[7])))
          + (((sB[8] + sB[9]) + (sB[10] + sB[11])) + ((sB[12] + sB[13]) + (sB[14] + sB[15])));

      unsigned wA[8], wB[8];
#pragma unroll
      for (int m = 0; m < 8; ++m) {
        asm("v_cvt_pk_bf16_f32 %0, %1, %2" : "=v"(wA[m]) : "v"(sA[2 * m]), "v"(sA[2 * m + 1]));
        asm("v_cvt_pk_bf16_f32 %0, %1, %2" : "=v"(wB[m]) : "v"(sB[2 * m]), "v"(sB[2 * m + 1]));
      }

      bf16x8 pbA[2], pbB[2];
#pragma unroll
      for (int ks = 0; ks < 2; ++ks) {
        unsigned a0 = wA[4 * ks],     a2 = wA[4 * ks + 2];
        unsigned a1 = wA[4 * ks + 1], a3 = wA[4 * ks + 3];
        asm("s_nop 1\n\tv_permlane32_swap_b32 %0, %1" : "+v"(a0), "+v"(a2));
        asm("s_nop 1\n\tv_permlane32_swap_b32 %0, %1" : "+v"(a1), "+v"(a3));
        u32x4 t; t[0] = a0; t[1] = a1; t[2] = a2; t[3] = a3;
        pbA[ks] = __builtin_bit_cast(bf16x8, t);
        unsigned b0 = wB[4 * ks],     b2 = wB[4 * ks + 2];
        unsigned b1 = wB[4 * ks + 1], b3 = wB[4 * ks + 3];
        asm("s_nop 1\n\tv_permlane32_swap_b32 %0, %1" : "+v"(b0), "+v"(b2));
        asm("s_nop 1\n\tv_permlane32_swap_b32 %0, %1" : "+v"(b1), "+v"(b3));
        u32x4 u; u[0] = b0; u[1] = b1; u[2] = b2; u[3] = b3;
        pbB[ks] = __builtin_bit_cast(bf16x8, u);
      }

      __builtin_amdgcn_s_setprio(1);
#pragma unroll
      for (int dblk = 0; dblk < 2; ++dblk) {
        const char* Vb = VsCur + (dblk * 32 + ql) * 128;
#pragma unroll
        for (int ks = 0; ks < 2; ++ks) {
          bf16x8 vf = *(const bf16x8*)(Vb + (((th * 4 + ks * 2 + h) ^ (ql & 7)) << 4));
          oA[dblk] = __builtin_amdgcn_mfma_f32_32x32x16_bf16(vf, pbA[ks], oA[dblk], 0, 0, 0);
          oB[dblk] = __builtin_amdgcn_mfma_f32_32x32x16_bf16(vf, pbB[ks], oB[dblk], 0, 0, 0);
        }
      }
      __builtin_amdgcn_s_setprio(0);

      asm volatile("s_waitcnt vmcnt(0)" ::: "memory");
      __builtin_amdgcn_s_barrier();
      __builtin_amdgcn_sched_barrier(0);
    }
  }
  __syncthreads();

  float pxA = lA, pyA = lA;
  asm("s_nop 1\n\tv_permlane32_swap_b32 %0, %1" : "+v"(pxA), "+v"(pyA));
  float lwA = lA + (h ? pxA : pyA);
  float pxB = lB, pyB = lB;
  asm("s_nop 1\n\tv_permlane32_swap_b32 %0, %1" : "+v"(pxB), "+v"(pyB));
  float lwB = lB + (h ? pxB : pyB);

  if (th == 1) {
    char* regA = SM + (qw * 2 + 0) * 8192;
    char* regB = SM + (qw * 2 + 1) * 8192;
#pragma unroll
    for (int dblk = 0; dblk < 2; ++dblk)
#pragma unroll
      for (int r = 0; r < 16; ++r) {
        int dl = dblk * 32 + (r & 3) + 8 * (r >> 2) + 4 * h;
        *(float*)(regA + dl * 128 + ql * 4) = oA[dblk][r];
        *(float*)(regB + dl * 128 + ql * 4) = oB[dblk][r];
      }
    if (h == 0) {
      *(float*)(SM + 32768 + (qw * 2 + 0) * 128 + ql * 4) = lwA;
      *(float*)(SM + 32768 + (qw * 2 + 1) * 128 + ql * 4) = lwB;
    }
  }
  __syncthreads();
  if (th == 0) {
    const char* regA = SM + (qw * 2 + 0) * 8192;
    const char* regB = SM + (qw * 2 + 1) * 8192;
#pragma unroll
    for (int dblk = 0; dblk < 2; ++dblk)
#pragma unroll
      for (int r = 0; r < 16; ++r) {
        int dl = dblk * 32 + (r & 3) + 8 * (r >> 2) + 4 * h;
        oA[dblk][r] += *(const float*)(regA + dl * 128 + ql * 4);
        oB[dblk][r] += *(const float*)(regB + dl * 128 + ql * 4);
      }
    float invA = 1.0f / (lwA + *(const float*)(SM + 32768 + (qw * 2 + 0) * 128 + ql * 4));
    float invB = 1.0f / (lwB + *(const float*)(SM + 32768 + (qw * 2 + 1) * 128 + ql * 4));
    long rowA = rowbase + q0w + ql;
    long rowB = rowA + 32;
#pragma unroll
    for (int dblk = 0; dblk < 2; ++dblk)
#pragma unroll
      for (int m = 0; m < 4; ++m) {
        ushort4 stA;
        stA.x = f2b(oA[dblk][4 * m + 0] * invA);
        stA.y = f2b(oA[dblk][4 * m + 1] * invA);
        stA.z = f2b(oA[dblk][4 * m + 2] * invA);
        stA.w = f2b(oA[dblk][4 * m + 3] * invA);
        *(ushort4*)(outb + rowA * 1024 + qcol + dblk * 32 + 8 * m + 4 * h) = stA;
        ushort4 stB;
        stB.x = f2b(oB[dblk][4 * m + 0] * invB);
        stB.y = f2b(oB[dblk][4 * m + 1] * invB);
        stB.z = f2b(oB[dblk][4 * m + 2] * invB);
        stB.w = f2b(oB[dblk][4 * m + 3] * invB);
        *(ushort4*)(outb + rowB * 1024 + qcol + dblk * 32 + 8 * m + 4 * h) = stB;
      }
  }
}

// ---------------------------------------------------------------- launch
extern "C" void kernel_launch(void* const* d_in, const int* in_sizes, int n_in,
                              void* d_out, int out_size, void* d_ws, size_t ws_size,
                              hipStream_t stream) {
  const float* x     = (const float*)d_in[0];  // [2,2048,1024]
  const float* w_qkv = (const float*)d_in[1];  // [3072,1024]
  const float* w_out = (const float*)d_in[2];  // [1024,1024]
  float* out = (float*)d_out;                  // [2,2048,1024] fp32

  char* ws = (char*)d_ws;
  u16* xb    = (u16*)(ws);                     //  8 MB  bf16 x
  u16* wqkvb = (u16*)(ws + 8388608);           //  6 MB  (Q rows pre-scaled)
  u16* woutb = (u16*)(ws + 14680064);          //  2 MB
  u16* qk    = (u16*)(ws + 16777216);          // 16 MB  [4096][2048] Q|K
  u16* vT    = (u16*)(ws + 33554432);          //  8 MB  [bh][64][2048]
  u16* attn  = (u16*)(ws + 41943040);          //  8 MB

  cast_all<<<2048, 256, 0, stream>>>(x, w_qkv, w_out, xb);

  // QKV projection: 8-phase 256x256 deep pipeline, fused QK/vT epilogue
  gemm_qkv<<<dim3(12, 16), 512, 0, stream>>>(xb, wqkvb, qk, vT);

  attn_fwd<<<dim3(16, 16, 2), 256, 0, stream>>>(qk, vT, attn);

  // output projection: TM=64 tile -> (8,64) = 512 blocks (R14-proven config)
  gemm_out<64><<<dim3(8, 64), 256, 0, stream>>>(attn, woutb, out, 4096, 1024, 1024);
}

// Round 21
// 102.968 us; speedup vs baseline: 1.0837x; 1.0388x over previous
//
#include <hip/hip_runtime.h>
#include <stdint.h>

typedef unsigned short u16;
typedef __bf16 bf16x8 __attribute__((ext_vector_type(8)));
typedef float f32x4 __attribute__((ext_vector_type(4)));
typedef float f32x16 __attribute__((ext_vector_type(16)));
typedef unsigned u32x4 __attribute__((ext_vector_type(4)));

#define DEVI __device__ __forceinline__

typedef __attribute__((address_space(1))) void gvoid;
typedef __attribute__((address_space(3))) void lvoid;

DEVI u16 f2b(float f) {
  unsigned x = __builtin_bit_cast(unsigned, f);
  return (u16)((x + 0x7fffu + ((x >> 16) & 1u)) >> 16);
}

DEVI float exp2g(float x) { return __builtin_amdgcn_exp2f(x); }

DEVI void gload_lds16(const void* g, void* l) {
  __builtin_amdgcn_global_load_lds((gvoid*)g, (lvoid*)l, 16, 0, 0);
}

// ---------------------------------------------------------------- fused cast
// ws bf16 image: xb (1M f4) | wqkvb (768K f4, first 256K scaled) | woutb (256K f4)
// Q out-feature rows of w_qkv scaled by 0.125*log2(e): folds attention scale +
// exp->exp2 into the QKV GEMM.
#define QSCALE 0.18033688011112042f

__global__ void cast_all(const float* __restrict__ x, const float* __restrict__ wqkv,
                         const float* __restrict__ wout, u16* __restrict__ outb) {
  int i = blockIdx.x * 256 + threadIdx.x;
  int stride = gridDim.x * 256;
  for (; i < 2097152; i += stride) {
    const float* src;
    float sc = 1.0f;
    if (i < 1048576) {
      src = x + 4 * (long)i;
    } else if (i < 1835008) {
      int j = i - 1048576;
      src = wqkv + 4 * (long)j;
      if (j < 262144) sc = QSCALE;
    } else {
      src = wout + 4 * (long)(i - 1835008);
    }
    float4 v = *(const float4*)src;
    ushort4 o;
    o.x = f2b(v.x * sc); o.y = f2b(v.y * sc); o.z = f2b(v.z * sc); o.w = f2b(v.w * sc);
    ((ushort4*)outb)[i] = o;
  }
}

// ---------------------------------------------------------------- GEMM C = A * B^T
// R14-proven single-buffer structure (32KB LDS, 3 blocks/CU for TM=128).
// OUT=1: fp32 row-major.  OUT=2: QKV fused epilogue (logical N=3072):
//   col < 2048 -> qk row-major [4096][2048]; col >= 2048 -> vT blocked:
//   Cv2[((tok>>11)*16 + (f>>6))*131072 + (f&63)*2048 + (tok&2047)]
template<int OUT, int TM>
__global__ __launch_bounds__(256)
void gemm_bt(const u16* __restrict__ A, const u16* __restrict__ B, void* __restrict__ Cv,
             void* __restrict__ Cv2, int M, int N, int K) {
  constexpr int MI = TM / 32;
  __shared__ u16 lA[TM * 64];
  __shared__ u16 lB[128 * 64];
  const int tid = threadIdx.x;
  const int lane = tid & 63;
  const int lr = lane & 15;
  const int lg = lane >> 4;
  const int wid = tid >> 6;
  const long bm = (long)blockIdx.y * TM;
  const long bn = (long)blockIdx.x * 128;
  const int wr = (wid >> 1) * (TM / 2);
  const int wc = (wid & 1) * 64;

  f32x4 acc[MI][4];
#pragma unroll
  for (int i = 0; i < MI; ++i)
#pragma unroll
    for (int j = 0; j < 4; ++j)
      acc[i][j] = (f32x4){0.f, 0.f, 0.f, 0.f};

  for (int k0 = 0; k0 < K; k0 += 64) {
#pragma unroll
    for (int q = 0; q < MI; ++q) {
      int bi = tid + q * 256;
      int row = bi >> 3;
      int col = ((bi & 7) ^ (row & 7)) * 8;
      gload_lds16(A + (bm + row) * (long)K + k0 + col, (char*)lA + bi * 16);
    }
#pragma unroll
    for (int q = 0; q < 4; ++q) {
      int bi = tid + q * 256;
      int row = bi >> 3;
      int col = ((bi & 7) ^ (row & 7)) * 8;
      gload_lds16(B + (bn + row) * (long)K + k0 + col, (char*)lB + bi * 16);
    }
    __syncthreads();
#pragma unroll
    for (int kk = 0; kk < 2; ++kk) {
      bf16x8 af[MI], bfr[4];
      int kb = kk * 4 + lg;
#pragma unroll
      for (int mi = 0; mi < MI; ++mi) {
        int row = wr + mi * 16 + lr;
        af[mi] = *(const bf16x8*)((const char*)lA + row * 128 + ((kb ^ (row & 7)) << 4));
      }
#pragma unroll
      for (int ni = 0; ni < 4; ++ni) {
        int row = wc + ni * 16 + lr;
        bfr[ni] = *(const bf16x8*)((const char*)lB + row * 128 + ((kb ^ (row & 7)) << 4));
      }
#pragma unroll
      for (int mi = 0; mi < MI; ++mi)
#pragma unroll
        for (int ni = 0; ni < 4; ++ni)
          acc[mi][ni] = __builtin_amdgcn_mfma_f32_16x16x32_bf16(af[mi], bfr[ni], acc[mi][ni], 0, 0, 0);
    }
    __syncthreads();
  }

  if (OUT == 2 && bn >= 2048) {
#pragma unroll
    for (int mi = 0; mi < MI; ++mi)
#pragma unroll
      for (int ni = 0; ni < 4; ++ni) {
        long tok = bm + wr + mi * 16 + lg * 4;
        long ff = bn + wc + ni * 16 + lr - 2048;
        ushort4 st;
        st.x = f2b(acc[mi][ni][0]);
        st.y = f2b(acc[mi][ni][1]);
        st.z = f2b(acc[mi][ni][2]);
        st.w = f2b(acc[mi][ni][3]);
        u16* dst = (u16*)Cv2 + (((tok >> 11) << 4) + (ff >> 6)) * 131072 + (ff & 63) * 2048 + (tok & 2047);
        *(ushort4*)dst = st;
      }
  } else {
    const long strideN = (OUT == 2) ? 2048 : N;
#pragma unroll
    for (int mi = 0; mi < MI; ++mi)
#pragma unroll
      for (int ni = 0; ni < 4; ++ni)
#pragma unroll
        for (int r = 0; r < 4; ++r) {
          long row = bm + wr + mi * 16 + lg * 4 + r;
          long col = bn + wc + ni * 16 + lr;
          float v = acc[mi][ni][r];
          if (OUT == 1) ((float*)Cv)[row * strideN + col] = v;
          else          ((u16*)Cv)[row * strideN + col] = f2b(v);
        }
  }
}

// ---------------------------------------------------------------- flash attention v11
// (best measured config, R14) 2-MFMA-per-LDS-read: each wave computes TWO 32-q
// blocks (A,B) sharing every K/V fragment read. 4 waves/block (th x qw = 2x2),
// q-tile 128, grid 512, 32x32x16 swapped MFMA, skip-max exp2 softmax (shift=0
// valid: logits bounded), in-register P via permlane32_swap, K+V^T staged via
// global_load_lds, double-buffer + issue-early/vmcnt(0)-barrier, XCD-aware
// bijective block swizzle.
__global__ __launch_bounds__(256, 2)
void attn_fwd(const u16* __restrict__ qk, const u16* __restrict__ vT,
              u16* __restrict__ outb) {
  __shared__ char SM[33280];

  const int tid = threadIdx.x;
  const int lane = tid & 63;
  const int wid = tid >> 6;
  const int ql = lane & 31;
  const int h  = lane >> 5;
  const int th = wid >> 1;
  const int qw = wid & 1;

  const int flat = blockIdx.x + (blockIdx.y << 4) + (blockIdx.z << 8);
  const int swz  = ((flat & 7) << 6) + (flat >> 3);
  const int qt = swz & 15;
  const int hd = (swz >> 4) & 15;
  const int b  = swz >> 8;

  const long rowbase = (long)b * 2048;
  const int qcol = hd * 64;
  const int kcol = 1024 + hd * 64;
  const int TSK = 64 * 2048;
  const long vhb = ((long)b * 16 + hd) * 131072;

  const int q0w = qt * 128 + qw * 64;
  bf16x8 qfA[4], qfB[4];
  {
    const u16* qpA = qk + (rowbase + q0w + ql) * 2048 + qcol + h * 8;
    const u16* qpB = qpA + 32 * 2048;
#pragma unroll
    for (int dblk = 0; dblk < 4; ++dblk) {
      qfA[dblk] = *(const bf16x8*)(qpA + dblk * 16);
      qfB[dblk] = *(const bf16x8*)(qpB + dblk * 16);
    }
  }

  float lA = 0.f, lB = 0.f;
  f32x16 oA[2], oB[2];
#pragma unroll
  for (int d = 0; d < 2; ++d)
#pragma unroll
    for (int r = 0; r < 16; ++r) { oA[d][r] = 0.f; oB[d][r] = 0.f; }

  const int c0 = tid, c1 = tid + 256;
  const int rk0 = c0 >> 3, ck0 = ((c0 & 7) ^ (rk0 & 7)) * 8;
  const int rk1 = c1 >> 3, ck1 = ((c1 & 7) ^ (rk1 & 7)) * 8;
  const int d0 = c0 * 16, d1 = c1 * 16;
  const u16* kp0 = qk + (rowbase + rk0) * 2048 + kcol + ck0;
  const u16* kp1 = qk + (rowbase + rk1) * 2048 + kcol + ck1;
  const u16* vp0 = vT + vhb + rk0 * 2048 + ck0;
  const u16* vp1 = vT + vhb + rk1 * 2048 + ck1;

  gload_lds16(kp0, SM + d0);          gload_lds16(kp1, SM + d1);
  gload_lds16(vp0, SM + 16384 + d0);  gload_lds16(vp1, SM + 16384 + d1);
  kp0 += TSK; kp1 += TSK; vp0 += 64; vp1 += 64;
  asm volatile("s_waitcnt vmcnt(0)" ::: "memory");
  __builtin_amdgcn_s_barrier();
  __builtin_amdgcn_sched_barrier(0);

  for (int tt = 0; tt < 16; ++tt) {
#pragma unroll
    for (int P = 0; P < 2; ++P) {
      char* KsCur = SM + P * 8192;
      char* VsCur = SM + 16384 + P * 8192;
      char* KsNxt = SM + (P ^ 1) * 8192;
      char* VsNxt = SM + 16384 + (P ^ 1) * 8192;

      gload_lds16(kp0, KsNxt + d0);  gload_lds16(kp1, KsNxt + d1);
      gload_lds16(vp0, VsNxt + d0);  gload_lds16(vp1, VsNxt + d1);
      kp0 += TSK; kp1 += TSK; vp0 += 64; vp1 += 64;

      f32x16 sA, sB;
#pragma unroll
      for (int r = 0; r < 16; ++r) { sA[r] = 0.f; sB[r] = 0.f; }
      const char* Kb = KsCur + (th * 32 + ql) * 128;
      __builtin_amdgcn_s_setprio(1);
#pragma unroll
      for (int kd = 0; kd < 4; ++kd) {
        bf16x8 kf = *(const bf16x8*)(Kb + (((kd * 2 + h) ^ (ql & 7)) << 4));
        sA = __builtin_amdgcn_mfma_f32_32x32x16_bf16(kf, qfA[kd], sA, 0, 0, 0);
        sB = __builtin_amdgcn_mfma_f32_32x32x16_bf16(kf, qfB[kd], sB, 0, 0, 0);
      }
      __builtin_amdgcn_s_setprio(0);

#pragma unroll
      for (int r = 0; r < 16; ++r) sA[r] = exp2g(sA[r]);
#pragma unroll
      for (int r = 0; r < 16; ++r) sB[r] = exp2g(sB[r]);
      lA += (((sA[0] + sA[1]) + (sA[2] + sA[3])) + ((sA[4] + sA[5]) + (sA[6] + sA[7])))
          + (((sA[8] + sA[9]) + (sA[10] + sA[11])) + ((sA[12] + sA[13]) + (sA[14] + sA[15])));
      lB += (((sB[0] + sB[1]) + (sB[2] + sB[3])) + ((sB[4] + sB[5]) + (sB[6] + sB[7])))
          + (((sB[8] + sB[9]) + (sB[10] + sB[11])) + ((sB[12] + sB[13]) + (sB[14] + sB[15])));

      unsigned wA[8], wB[8];
#pragma unroll
      for (int m = 0; m < 8; ++m) {
        asm("v_cvt_pk_bf16_f32 %0, %1, %2" : "=v"(wA[m]) : "v"(sA[2 * m]), "v"(sA[2 * m + 1]));
        asm("v_cvt_pk_bf16_f32 %0, %1, %2" : "=v"(wB[m]) : "v"(sB[2 * m]), "v"(sB[2 * m + 1]));
      }

      bf16x8 pbA[2], pbB[2];
#pragma unroll
      for (int ks = 0; ks < 2; ++ks) {
        unsigned a0 = wA[4 * ks],     a2 = wA[4 * ks + 2];
        unsigned a1 = wA[4 * ks + 1], a3 = wA[4 * ks + 3];
        asm("s_nop 1\n\tv_permlane32_swap_b32 %0, %1" : "+v"(a0), "+v"(a2));
        asm("s_nop 1\n\tv_permlane32_swap_b32 %0, %1" : "+v"(a1), "+v"(a3));
        u32x4 t; t[0] = a0; t[1] = a1; t[2] = a2; t[3] = a3;
        pbA[ks] = __builtin_bit_cast(bf16x8, t);
        unsigned b0 = wB[4 * ks],     b2 = wB[4 * ks + 2];
        unsigned b1 = wB[4 * ks + 1], b3 = wB[4 * ks + 3];
        asm("s_nop 1\n\tv_permlane32_swap_b32 %0, %1" : "+v"(b0), "+v"(b2));
        asm("s_nop 1\n\tv_permlane32_swap_b32 %0, %1" : "+v"(b1), "+v"(b3));
        u32x4 u; u[0] = b0; u[1] = b1; u[2] = b2; u[3] = b3;
        pbB[ks] = __builtin_bit_cast(bf16x8, u);
      }

      __builtin_amdgcn_s_setprio(1);
#pragma unroll
      for (int dblk = 0; dblk < 2; ++dblk) {
        const char* Vb = VsCur + (dblk * 32 + ql) * 128;
#pragma unroll
        for (int ks = 0; ks < 2; ++ks) {
          bf16x8 vf = *(const bf16x8*)(Vb + (((th * 4 + ks * 2 + h) ^ (ql & 7)) << 4));
          oA[dblk] = __builtin_amdgcn_mfma_f32_32x32x16_bf16(vf, pbA[ks], oA[dblk], 0, 0, 0);
          oB[dblk] = __builtin_amdgcn_mfma_f32_32x32x16_bf16(vf, pbB[ks], oB[dblk], 0, 0, 0);
        }
      }
      __builtin_amdgcn_s_setprio(0);

      asm volatile("s_waitcnt vmcnt(0)" ::: "memory");
      __builtin_amdgcn_s_barrier();
      __builtin_amdgcn_sched_barrier(0);
    }
  }
  __syncthreads();

  float pxA = lA, pyA = lA;
  asm("s_nop 1\n\tv_permlane32_swap_b32 %0, %1" : "+v"(pxA), "+v"(pyA));
  float lwA = lA + (h ? pxA : pyA);
  float pxB = lB, pyB = lB;
  asm("s_nop 1\n\tv_permlane32_swap_b32 %0, %1" : "+v"(pxB), "+v"(pyB));
  float lwB = lB + (h ? pxB : pyB);

  if (th == 1) {
    char* regA = SM + (qw * 2 + 0) * 8192;
    char* regB = SM + (qw * 2 + 1) * 8192;
#pragma unroll
    for (int dblk = 0; dblk < 2; ++dblk)
#pragma unroll
      for (int r = 0; r < 16; ++r) {
        int dl = dblk * 32 + (r & 3) + 8 * (r >> 2) + 4 * h;
        *(float*)(regA + dl * 128 + ql * 4) = oA[dblk][r];
        *(float*)(regB + dl * 128 + ql * 4) = oB[dblk][r];
      }
    if (h == 0) {
      *(float*)(SM + 32768 + (qw * 2 + 0) * 128 + ql * 4) = lwA;
      *(float*)(SM + 32768 + (qw * 2 + 1) * 128 + ql * 4) = lwB;
    }
  }
  __syncthreads();
  if (th == 0) {
    const char* regA = SM + (qw * 2 + 0) * 8192;
    const char* regB = SM + (qw * 2 + 1) * 8192;
#pragma unroll
    for (int dblk = 0; dblk < 2; ++dblk)
#pragma unroll
      for (int r = 0; r < 16; ++r) {
        int dl = dblk * 32 + (r & 3) + 8 * (r >> 2) + 4 * h;
        oA[dblk][r] += *(const float*)(regA + dl * 128 + ql * 4);
        oB[dblk][r] += *(const float*)(regB + dl * 128 + ql * 4);
      }
    float invA = 1.0f / (lwA + *(const float*)(SM + 32768 + (qw * 2 + 0) * 128 + ql * 4));
    float invB = 1.0f / (lwB + *(const float*)(SM + 32768 + (qw * 2 + 1) * 128 + ql * 4));
    long rowA = rowbase + q0w + ql;
    long rowB = rowA + 32;
#pragma unroll
    for (int dblk = 0; dblk < 2; ++dblk)
#pragma unroll
      for (int m = 0; m < 4; ++m) {
        ushort4 stA;
        stA.x = f2b(oA[dblk][4 * m + 0] * invA);
        stA.y = f2b(oA[dblk][4 * m + 1] * invA);
        stA.z = f2b(oA[dblk][4 * m + 2] * invA);
        stA.w = f2b(oA[dblk][4 * m + 3] * invA);
        *(ushort4*)(outb + rowA * 1024 + qcol + dblk * 32 + 8 * m + 4 * h) = stA;
        ushort4 stB;
        stB.x = f2b(oB[dblk][4 * m + 0] * invB);
        stB.y = f2b(oB[dblk][4 * m + 1] * invB);
        stB.z = f2b(oB[dblk][4 * m + 2] * invB);
        stB.w = f2b(oB[dblk][4 * m + 3] * invB);
        *(ushort4*)(outb + rowB * 1024 + qcol + dblk * 32 + 8 * m + 4 * h) = stB;
      }
  }
}

// ---------------------------------------------------------------- launch
extern "C" void kernel_launch(void* const* d_in, const int* in_sizes, int n_in,
                              void* d_out, int out_size, void* d_ws, size_t ws_size,
                              hipStream_t stream) {
  const float* x     = (const float*)d_in[0];  // [2,2048,1024]
  const float* w_qkv = (const float*)d_in[1];  // [3072,1024]
  const float* w_out = (const float*)d_in[2];  // [1024,1024]
  float* out = (float*)d_out;                  // [2,2048,1024] fp32

  char* ws = (char*)d_ws;
  u16* xb    = (u16*)(ws);                     //  8 MB  bf16 x
  u16* wqkvb = (u16*)(ws + 8388608);           //  6 MB  (Q rows pre-scaled)
  u16* woutb = (u16*)(ws + 14680064);          //  2 MB
  u16* qk    = (u16*)(ws + 16777216);          // 16 MB  [4096][2048] Q|K
  u16* vT    = (u16*)(ws + 33554432);          //  8 MB  [bh][64][2048]
  u16* attn  = (u16*)(ws + 41943040);          //  8 MB

  cast_all<<<2048, 256, 0, stream>>>(x, w_qkv, w_out, xb);

  // QKV projection with fused epilogue: Q,K -> qk row-major; V -> vT blocked
  gemm_bt<2, 128><<<dim3(24, 32), 256, 0, stream>>>(xb, wqkvb, qk, vT, 4096, 3072, 1024);

  attn_fwd<<<dim3(16, 16, 2), 256, 0, stream>>>(qk, vT, attn);

  // output projection: TM=64 tile -> (8,64) = 512 blocks (2 blocks/CU)
  gemm_bt<1, 64><<<dim3(8, 64), 256, 0, stream>>>(attn, woutb, out, nullptr, 4096, 1024, 1024);
}